// Round 3
// baseline (1276.107 us; speedup 1.0000x reference)
//
#include <hip/hip_runtime.h>

// BiGRU, B=512, T=512, D=16, H=64.
// Backward direction needs only ONE cell step (ys_b[0] = GRUCell(x[:,T-1,:], 0)).
//
// Structure: 4 waves per batch (block=256), K-split recurrent matvec, one
// barrier per step, all waves redundantly compute identical h (all waves read
// the same reduced LDS values post-barrier => identical h per run).
//
// Round-5 (this version): ds_add_f32 reduction.
//  - r/z partials atomically accumulate DIRECTLY into xg (projection phase
//    already deposited W_ih.x + biases there => free pre-initialized
//    accumulator, per-timestep unique storage, no parity).
//  - n-gate recurrent part (must stay separate: n = tanh(xn + r*(bhn + Wn.h)))
//    accumulates into a 4-deep rotating nbuf seeded with bhn 2 steps ahead
//    (4-deep => re-init write is barrier-separated from the last reader).
//  - post-barrier: 3 plain loads ARE the finished pre-activations
//    (was 12 loads + 9 tree adds).
//  - single accumulator per gate (3 interleaved 16-deep FMA chains refresh
//    every 6 cyc > 4 cyc dep latency => no stall, saves the pair-adds).
//  - rcp/exp fast gates, xn prefetched one step ahead, unroll x8 with
//    immediate DS offsets (kept from round 4).

#define Hh 64
#define Dd 16
#define Tt 512
#define Bb 512
#define CH 64   // timesteps per LDS chunk
#define NW 4    // waves per block
#define KW 16   // k-columns per wave

__device__ __forceinline__ float rcp_fast(float v) { return __builtin_amdgcn_rcpf(v); }
__device__ __forceinline__ float sigmoid_fast(float v) {
    return rcp_fast(1.0f + __expf(-v));
}
__device__ __forceinline__ float tanh_fast(float v) {
    return 1.0f - 2.0f * rcp_fast(__expf(2.0f * v) + 1.0f);
}
__device__ __forceinline__ float lane_bcast(float v, int k) {
    return __int_as_float(__builtin_amdgcn_readlane(__float_as_int(v), k));
}
__device__ __forceinline__ float dot4(float4 a, float4 b) {
    return a.x * b.x + a.y * b.y + a.z * b.z + a.w * b.w;
}
__device__ __forceinline__ void lds_add(float* p, float v) {
    __hip_atomic_fetch_add(p, v, __ATOMIC_RELAXED, __HIP_MEMORY_SCOPE_WORKGROUP);
}

// One recurrence step. S in [0,8): parity (S&3) and all LDS offsets are
// compile-time immediates. Consumes prefetched xn_n, prefetches row PF.
// nbuf[(S+2)&3] re-init is safe: its last reader was step S-2, separated
// from this write by barrier(S-1).
#define GSTEP(S, PF) do {                                                    \
    const float xnv = xn_n;                                                  \
    float pr = 0.f, pz = 0.f, pn = 0.f;                                      \
    _Pragma("unroll")                                                        \
    for (int kk = 0; kk < KW; ++kk) {                                        \
        const float hk = lane_bcast(h, k0 + kk);                             \
        pr += wr[kk] * hk;                                                   \
        pz += wz[kk] * hk;                                                   \
        pn += wn[kk] * hk;                                                   \
    }                                                                        \
    lds_add(xga + (S) * Hh, pr);                                             \
    lds_add(xga + CH * Hh + (S) * Hh, pz);                                   \
    lds_add(nb + (((S) & 3) * Hh), pn);                                      \
    nb[(((S) + 2) & 3) * Hh] = bhn;                                          \
    xn_n = xga[2 * CH * Hh + (PF) * Hh];                                     \
    __syncthreads();                                                         \
    const float ar  = xga[(S) * Hh];                                         \
    const float az  = xga[CH * Hh + (S) * Hh];                               \
    const float anr = nb[((S) & 3) * Hh];                                    \
    const float r = sigmoid_fast(ar);                                        \
    const float z = sigmoid_fast(az);                                        \
    const float n = tanh_fast(xnv + r * anr);                                \
    h = n + z * (h - n);                                                     \
} while (0)

__global__ __launch_bounds__(256, 2)
void bigru_fused_kernel(const float* __restrict__ x,
                        const float* __restrict__ w_ih_f, const float* __restrict__ w_hh_f,
                        const float* __restrict__ b_ih_f, const float* __restrict__ b_hh_f,
                        const float* __restrict__ w_ih_b, const float* __restrict__ w_hh_b,
                        const float* __restrict__ b_ih_b, const float* __restrict__ b_hh_b,
                        const float* __restrict__ fc_w,  const float* __restrict__ fc_b,
                        float* __restrict__ out)
{
    const int tid = threadIdx.x;
    const int j   = tid & 63;            // hidden unit
    const int w   = tid >> 6;            // wave id 0..3
    const int b   = blockIdx.x;          // batch element
    const int k0  = __builtin_amdgcn_readfirstlane(w << 4);  // SGPR k-base

    __shared__ __align__(16) float xbuf[CH * Dd];   // 4 KB raw x chunk
    __shared__ __align__(16) float xg[3][CH][Hh];   // 48 KB input proj (+bias) / r,z accumulators
    __shared__ __align__(16) float nbuf[4][Hh];     // 1 KB rotating n-gate accumulator

    // ---- recurrent weights: rows {j,64+j,128+j}, cols [k0,k0+16) -> 48 regs ----
    float wr[KW], wz[KW], wn[KW];
    {
        const float4* r0 = (const float4*)(w_hh_f + (size_t)j            * Hh + k0);
        const float4* r1 = (const float4*)(w_hh_f + (size_t)(Hh + j)     * Hh + k0);
        const float4* r2 = (const float4*)(w_hh_f + (size_t)(2 * Hh + j) * Hh + k0);
#pragma unroll
        for (int q = 0; q < KW / 4; ++q) {
            float4 a = r0[q]; wr[4*q] = a.x; wr[4*q+1] = a.y; wr[4*q+2] = a.z; wr[4*q+3] = a.w;
            float4 c = r1[q]; wz[4*q] = c.x; wz[4*q+1] = c.y; wz[4*q+2] = c.z; wz[4*q+3] = c.w;
            float4 e = r2[q]; wn[4*q] = e.x; wn[4*q+1] = e.y; wn[4*q+2] = e.z; wn[4*q+3] = e.w;
        }
    }
    // ---- input-projection weights (hoisted; 48 regs) + biases ----
    float4 wir[4], wiz[4], win[4];
    {
        const float4* p0 = (const float4*)(w_ih_f + (size_t)j            * Dd);
        const float4* p1 = (const float4*)(w_ih_f + (size_t)(Hh + j)     * Dd);
        const float4* p2 = (const float4*)(w_ih_f + (size_t)(2 * Hh + j) * Dd);
#pragma unroll
        for (int q = 0; q < 4; ++q) { wir[q] = p0[q]; wiz[q] = p1[q]; win[q] = p2[q]; }
    }
    const float bxr = b_ih_f[j]          + b_hh_f[j];
    const float bxz = b_ih_f[Hh + j]     + b_hh_f[Hh + j];
    const float bxn = b_ih_f[2 * Hh + j];
    const float bhn = b_hh_f[2 * Hh + j];

    float* nb = &nbuf[0][j];             // per-lane nbuf base
    // seed the first two rotation slots (steps 0,1 of the first chunk);
    // thereafter steps S init slot (S+2)&3, self-sustaining across chunks
    // (CH % 4 == 0). Cross-wave same-address same-value stores are benign.
    nb[0] = bhn;
    nb[Hh] = bhn;

    float h = 0.0f;
    const float* xrow = x + (size_t)b * Tt * Dd;

    for (int tc = 0; tc < Tt / CH; ++tc) {
        __syncthreads();  // previous chunk fully consumed (incl. nbuf seeds)
        // stage 64 timesteps (1024 floats): one float4 per thread, coalesced
        ((float4*)xbuf)[tid] = ((const float4*)(xrow + (size_t)tc * CH * Dd))[tid];
        __syncthreads();

        // ---- input projections: wave w covers tt in [16w, 16w+16) ----
#pragma unroll 4
        for (int tt2 = 0; tt2 < KW; ++tt2) {
            const int tt = (w << 4) + tt2;
            const float4* x4 = (const float4*)(xbuf + tt * Dd);
            float4 xv0 = x4[0], xv1 = x4[1], xv2 = x4[2], xv3 = x4[3];
            float ar = bxr + dot4(wir[0], xv0) + dot4(wir[1], xv1) + dot4(wir[2], xv2) + dot4(wir[3], xv3);
            float az = bxz + dot4(wiz[0], xv0) + dot4(wiz[1], xv1) + dot4(wiz[2], xv2) + dot4(wiz[3], xv3);
            float an = bxn + dot4(win[0], xv0) + dot4(win[1], xv1) + dot4(win[2], xv2) + dot4(win[3], xv3);
            xg[0][tt][j] = ar;
            xg[1][tt][j] = az;
            xg[2][tt][j] = an;
        }
        __syncthreads();

        // ---- recurrence: K-split matvec, ds_add reduce, one barrier/step ----
        float* xga = &xg[0][0][j];
        float xn_n = xga[2 * CH * Hh];

        for (int tt = 0; tt < CH; tt += 8) {
            if (tt < CH - 8) {
                GSTEP(0, 1); GSTEP(1, 2); GSTEP(2, 3); GSTEP(3, 4);
                GSTEP(4, 5); GSTEP(5, 6); GSTEP(6, 7); GSTEP(7, 8);
            } else {
                // last group: final prefetch clamped in-array (dead value)
                GSTEP(0, 1); GSTEP(1, 2); GSTEP(2, 3); GSTEP(3, 4);
                GSTEP(4, 5); GSTEP(5, 6); GSTEP(6, 7); GSTEP(7, 7);
            }
            xga += 8 * Hh;
        }
    }

    // ---- tail: backward single cell step + FC, wave 0 only ----
    if (w == 0) {
        float ar   = b_ih_b[j]          + b_hh_b[j];
        float az   = b_ih_b[Hh + j]     + b_hh_b[Hh + j];
        float axn  = b_ih_b[2 * Hh + j];
        float bhnb = b_hh_b[2 * Hh + j];
        {
            const float4* xl = (const float4*)(xbuf + 63 * Dd);  // t = 511
            const float4* q0 = (const float4*)(w_ih_b + (size_t)j            * Dd);
            const float4* q1 = (const float4*)(w_ih_b + (size_t)(Hh + j)     * Dd);
            const float4* q2 = (const float4*)(w_ih_b + (size_t)(2 * Hh + j) * Dd);
#pragma unroll
            for (int q = 0; q < 4; ++q) {
                float4 xv = xl[q];
                float4 a = q0[q], c = q1[q], e = q2[q];
                ar  += a.x * xv.x + a.y * xv.y + a.z * xv.z + a.w * xv.w;
                az  += c.x * xv.x + c.y * xv.y + c.z * xv.z + c.w * xv.w;
                axn += e.x * xv.x + e.y * xv.y + e.z * xv.z + e.w * xv.w;
            }
        }
        float rb = sigmoid_fast(ar);
        float zb = sigmoid_fast(az);
        float nb2 = tanh_fast(axn + rb * bhnb);
        float hb = (1.0f - zb) * nb2;   // h0 = 0

        float v = fc_w[j] * h + fc_w[Hh + j] * hb;
#pragma unroll
        for (int off = 32; off > 0; off >>= 1)
            v += __shfl_xor(v, off, 64);
        if (j == 0) out[b] = v + fc_b[0];
    }
}

extern "C" void kernel_launch(void* const* d_in, const int* in_sizes, int n_in,
                              void* d_out, int out_size, void* d_ws, size_t ws_size,
                              hipStream_t stream) {
    const float* x      = (const float*)d_in[0];
    const float* w_ih_f = (const float*)d_in[1];
    const float* w_hh_f = (const float*)d_in[2];
    const float* b_ih_f = (const float*)d_in[3];
    const float* b_hh_f = (const float*)d_in[4];
    const float* w_ih_b = (const float*)d_in[5];
    const float* w_hh_b = (const float*)d_in[6];
    const float* b_ih_b = (const float*)d_in[7];
    const float* b_hh_b = (const float*)d_in[8];
    const float* fc_w   = (const float*)d_in[9];
    const float* fc_b   = (const float*)d_in[10];

    bigru_fused_kernel<<<dim3(Bb), dim3(NW * 64), 0, stream>>>(
        x, w_ih_f, w_hh_f, b_ih_f, b_hh_f,
        w_ih_b, w_hh_b, b_ih_b, b_hh_b, fc_w, fc_b,
        (float*)d_out);
}

// Round 4
// 407.631 us; speedup vs baseline: 3.1305x; 3.1305x over previous
//
#include <hip/hip_runtime.h>

// BiGRU, B=512, T=512, D=16, H=64.
// Backward direction needs only ONE cell step (ys_b[0] = GRUCell(x[:,T-1,:], 0)).
//
// Round-6: two-kernel split (guarded by ws_size).
//  Kernel 1 (proj): xg[b][t][192] = W_ih.x + b_ih (+b_hh for r,z) for all b,t.
//    Embarrassingly parallel, full occupancy, ~201MB write, memory-bound.
//  Kernel 2 (rec): ONE WAVE PER BATCH ELEMENT, zero sync. W_hh (192 floats)
//    lives in VGPRs (projection moved out => ~225 live regs < 256, no AGPR
//    copy disaster). Per step: 64 readlane(h) + 192 FMA + gates. No barrier,
//    no LDS, no cross-wave redundancy. xg streamed with 2-step reg prefetch.
//  Fallback: if ws_size < 201MB, run the verified round-2 monolithic kernel.

#define Hh 64
#define Dd 16
#define Tt 512
#define Bb 512
#define G3 192   // 3*H
#define CH 64    // fallback kernel: timesteps per LDS chunk
#define NW 4     // fallback kernel: waves per block
#define KW 16    // fallback kernel: k-columns per wave

__device__ __forceinline__ float rcp_fast(float v) { return __builtin_amdgcn_rcpf(v); }
__device__ __forceinline__ float sigmoid_fast(float v) {
    return rcp_fast(1.0f + __expf(-v));
}
__device__ __forceinline__ float tanh_fast(float v) {
    return 1.0f - 2.0f * rcp_fast(__expf(2.0f * v) + 1.0f);
}
__device__ __forceinline__ float lane_bcast(float v, int k) {
    return __int_as_float(__builtin_amdgcn_readlane(__float_as_int(v), k));
}
__device__ __forceinline__ float dot4(float4 a, float4 b) {
    return a.x * b.x + a.y * b.y + a.z * b.z + a.w * b.w;
}

// ---------------------------------------------------------------------------
// Kernel 1: input projection. grid (Bb, 16), block 192 (3 waves).
// Block (b, tc) computes xg[b][tc*32 .. tc*32+32)[0..192).
// ---------------------------------------------------------------------------
__global__ __launch_bounds__(192, 4)
void proj_kernel(const float* __restrict__ x,
                 const float* __restrict__ w_ih_f,
                 const float* __restrict__ b_ih_f, const float* __restrict__ b_hh_f,
                 float* __restrict__ xg)
{
    const int j  = threadIdx.x;        // output row 0..191 (r:0-63, z:64-127, n:128-191)
    const int b  = blockIdx.x;
    const int tc = blockIdx.y;

    __shared__ __align__(16) float xs[32 * Dd];   // 2 KB

    if (j < 128)
        ((float4*)xs)[j] = ((const float4*)(x + ((size_t)b * Tt + (size_t)tc * 32) * Dd))[j];

    float4 w0, w1, w2, w3;
    {
        const float4* p = (const float4*)(w_ih_f + (size_t)j * Dd);
        w0 = p[0]; w1 = p[1]; w2 = p[2]; w3 = p[3];
    }
    // r,z rows get b_ih + b_hh folded; n rows get b_ih only (b_hh_n enters
    // inside the r* term in the recurrence).
    const float bias = (j < 128) ? (b_ih_f[j] + b_hh_f[j]) : b_ih_f[j];
    __syncthreads();

    float* op = xg + ((size_t)b * Tt + (size_t)tc * 32) * G3 + j;
#pragma unroll 4
    for (int t = 0; t < 32; ++t) {
        const float4* xv = (const float4*)(xs + t * Dd);
        float4 x0 = xv[0], x1 = xv[1], x2 = xv[2], x3 = xv[3];
        float a = bias + dot4(w0, x0) + dot4(w1, x1) + dot4(w2, x2) + dot4(w3, x3);
        op[(size_t)t * G3] = a;
    }
}

// ---------------------------------------------------------------------------
// Kernel 2: recurrence. grid (Bb), block 64 = ONE wave per batch element.
// ---------------------------------------------------------------------------
__global__ __launch_bounds__(64, 1)
void rec_kernel(const float* __restrict__ xg,
                const float* __restrict__ w_hh_f, const float* __restrict__ b_hh_f,
                const float* __restrict__ x,
                const float* __restrict__ w_ih_b, const float* __restrict__ w_hh_b,
                const float* __restrict__ b_ih_b, const float* __restrict__ b_hh_b,
                const float* __restrict__ fc_w,  const float* __restrict__ fc_b,
                float* __restrict__ out)
{
    const int j = threadIdx.x;   // hidden unit 0..63
    const int b = blockIdx.x;

    // W_hh rows {j, 64+j, 128+j}: full 64 columns each -> 192 VGPRs.
    float wr[Hh], wz[Hh], wn[Hh];
    {
        const float4* r0 = (const float4*)(w_hh_f + (size_t)j            * Hh);
        const float4* r1 = (const float4*)(w_hh_f + (size_t)(Hh + j)     * Hh);
        const float4* r2 = (const float4*)(w_hh_f + (size_t)(2 * Hh + j) * Hh);
#pragma unroll
        for (int q = 0; q < Hh / 4; ++q) {
            float4 a = r0[q]; wr[4*q] = a.x; wr[4*q+1] = a.y; wr[4*q+2] = a.z; wr[4*q+3] = a.w;
            float4 c = r1[q]; wz[4*q] = c.x; wz[4*q+1] = c.y; wz[4*q+2] = c.z; wz[4*q+3] = c.w;
            float4 e = r2[q]; wn[4*q] = e.x; wn[4*q+1] = e.y; wn[4*q+2] = e.z; wn[4*q+3] = e.w;
        }
    }
    const float bhn = b_hh_f[2 * Hh + j];

    const float* xp = xg + (size_t)b * Tt * G3;

    // 2-deep register prefetch of the per-step projections (768 B/step).
    float arE = xp[j],      azE = xp[Hh + j],      anE = xp[2 * Hh + j];
    float arO = xp[G3 + j], azO = xp[G3 + Hh + j], anO = xp[G3 + 2 * Hh + j];

    float h = 0.0f;

#define RSTEP(XR, XZ, XN) do {                                               \
        float sr = (XR), sz = (XZ), sn = bhn;                                \
        _Pragma("unroll")                                                    \
        for (int k = 0; k < Hh; ++k) {                                       \
            const float hk = lane_bcast(h, k);                               \
            sr += wr[k] * hk;                                                \
            sz += wz[k] * hk;                                                \
            sn += wn[k] * hk;                                                \
        }                                                                    \
        const float r = sigmoid_fast(sr);                                    \
        const float z = sigmoid_fast(sz);                                    \
        const float n = tanh_fast((XN) + r * sn);                            \
        h = n + z * (h - n);                                                 \
    } while (0)

    for (int t = 0; t < Tt; t += 2) {
        // even step: consume E, prefetch t+2 into E
        {
            const float xr = arE, xz = azE, xn = anE;
            const int tp = (t + 2 < Tt) ? (t + 2) : (Tt - 1);   // clamped (dead at tail)
            const float* pf = xp + (size_t)tp * G3;
            arE = pf[j]; azE = pf[Hh + j]; anE = pf[2 * Hh + j];
            RSTEP(xr, xz, xn);
        }
        // odd step: consume O, prefetch t+3 into O
        {
            const float xr = arO, xz = azO, xn = anO;
            const int tp = (t + 3 < Tt) ? (t + 3) : (Tt - 1);
            const float* pf = xp + (size_t)tp * G3;
            arO = pf[j]; azO = pf[Hh + j]; anO = pf[2 * Hh + j];
            RSTEP(xr, xz, xn);
        }
    }
#undef RSTEP

    // ---- tail: backward single cell step + FC ----
    float ar   = b_ih_b[j]          + b_hh_b[j];
    float az   = b_ih_b[Hh + j]     + b_hh_b[Hh + j];
    float axn  = b_ih_b[2 * Hh + j];
    const float bhnb = b_hh_b[2 * Hh + j];
    {
        const float4* xl = (const float4*)(x + ((size_t)b * Tt + (Tt - 1)) * Dd);
        float4 xv0 = xl[0], xv1 = xl[1], xv2 = xl[2], xv3 = xl[3];
        const float4* q0 = (const float4*)(w_ih_b + (size_t)j            * Dd);
        const float4* q1 = (const float4*)(w_ih_b + (size_t)(Hh + j)     * Dd);
        const float4* q2 = (const float4*)(w_ih_b + (size_t)(2 * Hh + j) * Dd);
        ar  += dot4(q0[0], xv0) + dot4(q0[1], xv1) + dot4(q0[2], xv2) + dot4(q0[3], xv3);
        az  += dot4(q1[0], xv0) + dot4(q1[1], xv1) + dot4(q1[2], xv2) + dot4(q1[3], xv3);
        axn += dot4(q2[0], xv0) + dot4(q2[1], xv1) + dot4(q2[2], xv2) + dot4(q2[3], xv3);
    }
    const float rb = sigmoid_fast(ar);
    const float zb = sigmoid_fast(az);
    const float nb = tanh_fast(axn + rb * bhnb);
    const float hb = (1.0f - zb) * nb;   // h0 = 0

    float v = fc_w[j] * h + fc_w[Hh + j] * hb;
#pragma unroll
    for (int off = 32; off > 0; off >>= 1)
        v += __shfl_xor(v, off, 64);
    if (j == 0) out[b] = v + fc_b[0];
}

// ---------------------------------------------------------------------------
// Fallback: verified round-2 monolithic kernel (318 us), used if ws too small.
// ---------------------------------------------------------------------------
#define GSTEP(S, PF) do {                                                    \
    const float xr = xr_n, xz = xz_n, xnv = xn_n;                            \
    float pr0 = 0.f, pr1 = 0.f, pz0 = 0.f, pz1 = 0.f, pn0 = 0.f, pn1 = 0.f; \
    _Pragma("unroll")                                                        \
    for (int kk = 0; kk < 8; ++kk) {                                         \
        const float ha = lane_bcast(h, k0 + kk);                             \
        const float hb = lane_bcast(h, k0 + kk + 8);                         \
        pr0 += wr[kk] * ha;   pr1 += wr[kk + 8] * hb;                        \
        pz0 += wz[kk] * ha;   pz1 += wz[kk + 8] * hb;                        \
        pn0 += wn[kk] * ha;   pn1 += wn[kk + 8] * hb;                        \
    }                                                                        \
    pw[((S)&1) * 768 +   0] = pr0 + pr1;                                     \
    pw[((S)&1) * 768 +  64] = pz0 + pz1;                                     \
    pw[((S)&1) * 768 + 128] = pn0 + pn1;                                     \
    xr_n = xgp[(PF) * Hh];                                                   \
    xz_n = xgp[CH * Hh + (PF) * Hh];                                         \
    xn_n = xgp[2 * CH * Hh + (PF) * Hh];                                     \
    __syncthreads();                                                         \
    const float q00 = prd[((S)&1) * 768 +   0];                              \
    const float q01 = prd[((S)&1) * 768 +  64];                              \
    const float q02 = prd[((S)&1) * 768 + 128];                              \
    const float q10 = prd[((S)&1) * 768 + 192];                              \
    const float q11 = prd[((S)&1) * 768 + 256];                              \
    const float q12 = prd[((S)&1) * 768 + 320];                              \
    const float q20 = prd[((S)&1) * 768 + 384];                              \
    const float q21 = prd[((S)&1) * 768 + 448];                              \
    const float q22 = prd[((S)&1) * 768 + 512];                              \
    const float q30 = prd[((S)&1) * 768 + 576];                              \
    const float q31 = prd[((S)&1) * 768 + 640];                              \
    const float q32 = prd[((S)&1) * 768 + 704];                              \
    const float ar = xr  + ((q00 + q10) + (q20 + q30));                      \
    const float az = xz  + ((q01 + q11) + (q21 + q31));                      \
    const float an = bhn + ((q02 + q12) + (q22 + q32));                      \
    const float r = sigmoid_fast(ar);                                        \
    const float z = sigmoid_fast(az);                                        \
    const float n = tanh_fast(xnv + r * an);                                 \
    h = n + z * (h - n);                                                     \
} while (0)

__global__ __launch_bounds__(256, 2)
void bigru_fused_kernel(const float* __restrict__ x,
                        const float* __restrict__ w_ih_f, const float* __restrict__ w_hh_f,
                        const float* __restrict__ b_ih_f, const float* __restrict__ b_hh_f,
                        const float* __restrict__ w_ih_b, const float* __restrict__ w_hh_b,
                        const float* __restrict__ b_ih_b, const float* __restrict__ b_hh_b,
                        const float* __restrict__ fc_w,  const float* __restrict__ fc_b,
                        float* __restrict__ out)
{
    const int tid = threadIdx.x;
    const int j   = tid & 63;
    const int w   = tid >> 6;
    const int b   = blockIdx.x;
    const int k0  = __builtin_amdgcn_readfirstlane(w << 4);

    __shared__ __align__(16) float xbuf[CH * Dd];
    __shared__ __align__(16) float xg[3][CH][Hh];
    __shared__ __align__(16) float parts[2][NW][3][Hh];

    float wr[KW], wz[KW], wn[KW];
    {
        const float4* r0 = (const float4*)(w_hh_f + (size_t)j            * Hh + k0);
        const float4* r1 = (const float4*)(w_hh_f + (size_t)(Hh + j)     * Hh + k0);
        const float4* r2 = (const float4*)(w_hh_f + (size_t)(2 * Hh + j) * Hh + k0);
#pragma unroll
        for (int q = 0; q < KW / 4; ++q) {
            float4 a = r0[q]; wr[4*q] = a.x; wr[4*q+1] = a.y; wr[4*q+2] = a.z; wr[4*q+3] = a.w;
            float4 c = r1[q]; wz[4*q] = c.x; wz[4*q+1] = c.y; wz[4*q+2] = c.z; wz[4*q+3] = c.w;
            float4 e = r2[q]; wn[4*q] = e.x; wn[4*q+1] = e.y; wn[4*q+2] = e.z; wn[4*q+3] = e.w;
        }
    }
    float4 wir[4], wiz[4], win[4];
    {
        const float4* p0 = (const float4*)(w_ih_f + (size_t)j            * Dd);
        const float4* p1 = (const float4*)(w_ih_f + (size_t)(Hh + j)     * Dd);
        const float4* p2 = (const float4*)(w_ih_f + (size_t)(2 * Hh + j) * Dd);
#pragma unroll
        for (int q = 0; q < 4; ++q) { wir[q] = p0[q]; wiz[q] = p1[q]; win[q] = p2[q]; }
    }
    const float bxr = b_ih_f[j]          + b_hh_f[j];
    const float bxz = b_ih_f[Hh + j]     + b_hh_f[Hh + j];
    const float bxn = b_ih_f[2 * Hh + j];
    const float bhn = b_hh_f[2 * Hh + j];

    float*       pw  = &parts[0][w][0][j];
    const float* prd = &parts[0][0][0][j];

    float h = 0.0f;
    const float* xrow = x + (size_t)b * Tt * Dd;

    for (int tc = 0; tc < Tt / CH; ++tc) {
        __syncthreads();
        ((float4*)xbuf)[tid] = ((const float4*)(xrow + (size_t)tc * CH * Dd))[tid];
        __syncthreads();

#pragma unroll 4
        for (int tt2 = 0; tt2 < KW; ++tt2) {
            const int tt = (w << 4) + tt2;
            const float4* x4 = (const float4*)(xbuf + tt * Dd);
            float4 xv0 = x4[0], xv1 = x4[1], xv2 = x4[2], xv3 = x4[3];
            float ar = bxr + dot4(wir[0], xv0) + dot4(wir[1], xv1) + dot4(wir[2], xv2) + dot4(wir[3], xv3);
            float az = bxz + dot4(wiz[0], xv0) + dot4(wiz[1], xv1) + dot4(wiz[2], xv2) + dot4(wiz[3], xv3);
            float an = bxn + dot4(win[0], xv0) + dot4(win[1], xv1) + dot4(win[2], xv2) + dot4(win[3], xv3);
            xg[0][tt][j] = ar;
            xg[1][tt][j] = az;
            xg[2][tt][j] = an;
        }
        __syncthreads();

        const float* xgp = &xg[0][0][j];
        float xr_n = xgp[0];
        float xz_n = xgp[CH * Hh];
        float xn_n = xgp[2 * CH * Hh];

        for (int tt = 0; tt < CH; tt += 8) {
            if (tt < CH - 8) {
                GSTEP(0, 1); GSTEP(1, 2); GSTEP(2, 3); GSTEP(3, 4);
                GSTEP(4, 5); GSTEP(5, 6); GSTEP(6, 7); GSTEP(7, 8);
            } else {
                GSTEP(0, 1); GSTEP(1, 2); GSTEP(2, 3); GSTEP(3, 4);
                GSTEP(4, 5); GSTEP(5, 6); GSTEP(6, 7); GSTEP(7, 7);
            }
            xgp += 8 * Hh;
        }
    }

    if (w == 0) {
        float ar   = b_ih_b[j]          + b_hh_b[j];
        float az   = b_ih_b[Hh + j]     + b_hh_b[Hh + j];
        float axn  = b_ih_b[2 * Hh + j];
        float bhnb = b_hh_b[2 * Hh + j];
        {
            const float4* xl = (const float4*)(xbuf + 63 * Dd);
            const float4* q0 = (const float4*)(w_ih_b + (size_t)j            * Dd);
            const float4* q1 = (const float4*)(w_ih_b + (size_t)(Hh + j)     * Dd);
            const float4* q2 = (const float4*)(w_ih_b + (size_t)(2 * Hh + j) * Dd);
#pragma unroll
            for (int q = 0; q < 4; ++q) {
                float4 xv = xl[q];
                float4 a = q0[q], c = q1[q], e = q2[q];
                ar  += a.x * xv.x + a.y * xv.y + a.z * xv.z + a.w * xv.w;
                az  += c.x * xv.x + c.y * xv.y + c.z * xv.z + c.w * xv.w;
                axn += e.x * xv.x + e.y * xv.y + e.z * xv.z + e.w * xv.w;
            }
        }
        float rb = sigmoid_fast(ar);
        float zb = sigmoid_fast(az);
        float nb2 = tanh_fast(axn + rb * bhnb);
        float hb = (1.0f - zb) * nb2;

        float v = fc_w[j] * h + fc_w[Hh + j] * hb;
#pragma unroll
        for (int off = 32; off > 0; off >>= 1)
            v += __shfl_xor(v, off, 64);
        if (j == 0) out[b] = v + fc_b[0];
    }
}

extern "C" void kernel_launch(void* const* d_in, const int* in_sizes, int n_in,
                              void* d_out, int out_size, void* d_ws, size_t ws_size,
                              hipStream_t stream) {
    const float* x      = (const float*)d_in[0];
    const float* w_ih_f = (const float*)d_in[1];
    const float* w_hh_f = (const float*)d_in[2];
    const float* b_ih_f = (const float*)d_in[3];
    const float* b_hh_f = (const float*)d_in[4];
    const float* w_ih_b = (const float*)d_in[5];
    const float* w_hh_b = (const float*)d_in[6];
    const float* b_ih_b = (const float*)d_in[7];
    const float* b_hh_b = (const float*)d_in[8];
    const float* fc_w   = (const float*)d_in[9];
    const float* fc_b   = (const float*)d_in[10];

    const size_t need = (size_t)Bb * Tt * G3 * sizeof(float);   // 201,326,592 B
    if (d_ws != nullptr && ws_size >= need) {
        float* xg = (float*)d_ws;
        proj_kernel<<<dim3(Bb, 16), dim3(192), 0, stream>>>(
            x, w_ih_f, b_ih_f, b_hh_f, xg);
        rec_kernel<<<dim3(Bb), dim3(64), 0, stream>>>(
            xg, w_hh_f, b_hh_f, x,
            w_ih_b, w_hh_b, b_ih_b, b_hh_b, fc_w, fc_b,
            (float*)d_out);
    } else {
        bigru_fused_kernel<<<dim3(Bb), dim3(NW * 64), 0, stream>>>(
            x, w_ih_f, w_hh_f, b_ih_f, b_hh_f,
            w_ih_b, w_hh_b, b_ih_b, b_hh_b, fc_w, fc_b,
            (float*)d_out);
    }
}